// Round 18
// baseline (10465.014 us; speedup 1.0000x reference)
//
#include <hip/hip_runtime.h>
#include <hip/hip_bf16.h>

#define BB 16
#define LL 1024
#define EE 128
#define HH 4
#define DD 128
#define NN 1025
#define HE 512
#define AL 0.2f
#define EPSV 1e-6f

// workspace float offsets (total ~633416 floats = 2.53 MB)
#define O_WH 0
#define O_F1 524800
#define O_F2 528900
#define O_W2 533000
#define O_WR 535048
#define O_Z  600584
#define O_U  600648

// ---- K1: Wh[h,n,f] = sum_e emb[n,e] * W_enc[h,e,f]  (emb row 0 = 0) --------
__global__ void VGNN_27049704030896_kernel(const float* embed,
                                           const float* W_enc,
                                           float* Wh) {
  int n = blockIdx.x;
  int h = blockIdx.y;
  int f = threadIdx.x;
  float acc = 0.0f;
  if (n > 0) {
    for (int e = 0; e < EE; e++) {
      acc += embed[n * EE + e] * W_enc[(h * EE + e) * EE + f];
    }
  }
  Wh[(h * NN + n) * EE + f] = acc;
}

// ---- K2: f1/f2 row dots (f1: row term a_enc_src, f2: col term a_enc_dst) --
__global__ void k_f12(const float* Wh, const float* a_src,
                      const float* a_dst, float* f1, float* f2) {
  __shared__ float r1[EE];
  __shared__ float r2[EE];
  int n = blockIdx.x;
  int h = blockIdx.y;
  int f = threadIdx.x;
  float w = Wh[(h * NN + n) * EE + f];
  r1[f] = w * a_src[h * EE + f];
  r2[f] = w * a_dst[h * EE + f];
  __syncthreads();
  for (int s = 64; s > 0; s >>= 1) {
    if (f < s) { r1[f] += r1[f + s]; r2[f] += r2[f + s]; }
    __syncthreads();
  }
  if (f == 0) { f1[h * NN + n] = r1[0]; f2[h * NN + n] = r2[0]; }
}

// ---- K3: w2[h,k] = sum_d W_dec[h,k,d] * a_dec_dst[h,d] --------------------
__global__ void k_w2(const float* W_dec, const float* a_vec, float* w2) {
  int k = blockIdx.x * 128 + threadIdx.x;
  int h = blockIdx.y;
  float s = 0.0f;
  for (int d = 0; d < DD; d++) {
    s += W_dec[(h * HE + k) * DD + d] * a_vec[h * DD + d];
  }
  w2[h * HE + k] = s;
}

// ---- K4: zero U and z -----------------------------------------------------
__global__ void k_zero(float* U, float* z) {
  int t = blockIdx.x * 256 + threadIdx.x;
  if (t < BB * HH * HE) U[t] = 0.0f;
  if (t < BB * HH) z[t] = 0.0f;
}

// ---- K5: pass 1: per row -> enc -> LN -> elu -> g2 -> weight, z -----------
__global__ void k_enc(const int* data, const float* Wh, const float* f1,
                      const float* f2, const float* g_enc,
                      const float* b_enc, const float* w2,
                      float* wrow, float* zacc) {
  int i = blockIdx.x;
  int b = blockIdx.y;
  int f = threadIdx.x;
  if (data[b * LL + i] == 0) return;   // block-uniform
  __shared__ float wj[NN];
  __shared__ float red[EE];
  float x[HH];
  for (int h = 0; h < HH; h++) {
    float f1i = f1[h * NN + i];
    for (int j = f; j < NN; j += EE) {
      float w = 0.0f;
      if (j < LL) {
        if (data[b * LL + j] != 0) {
          float lg = f1i + f2[h * NN + j];
          if (lg < 0.0f) lg = AL * lg;
          w = expf(lg);
        }
      }
      wj[j] = w;
    }
    __syncthreads();
    float p = 0.0f;
    for (int j = f; j < NN; j += EE) p += wj[j];
    red[f] = p;
    __syncthreads();
    for (int s = 64; s > 0; s >>= 1) {
      if (f < s) red[f] += red[f + s];
      __syncthreads();
    }
    float den = red[0];
    __syncthreads();
    float acc = 0.0f;
    for (int j = 0; j < LL; j++) {
      float w = wj[j];
      if (w != 0.0f) acc += w * Wh[(h * NN + j) * EE + f];
    }
    float v = acc / den;
    x[h] = (v > 0.0f) ? v : (expf(v) - 1.0f);
    __syncthreads();
  }
  red[f] = x[0] + x[1] + x[2] + x[3];
  __syncthreads();
  for (int s = 64; s > 0; s >>= 1) {
    if (f < s) red[f] += red[f + s];
    __syncthreads();
  }
  float mu = red[0] / 512.0f;
  __syncthreads();
  float q = 0.0f;
  for (int h = 0; h < HH; h++) { float d = x[h] - mu; q += d * d; }
  red[f] = q;
  __syncthreads();
  for (int s = 64; s > 0; s >>= 1) {
    if (f < s) red[f] += red[f + s];
    __syncthreads();
  }
  float sd = sqrtf(red[0] / 511.0f);
  float inv = 1.0f / (sd + EPSV);
  __syncthreads();
  float e4[HH];
  for (int h = 0; h < HH; h++) {
    float v = g_enc[h * EE + f] * (x[h] - mu) * inv + b_enc[h * EE + f];
    e4[h] = (v > 0.0f) ? v : (expf(v) - 1.0f);
  }
  for (int hp = 0; hp < HH; hp++) {
    float p = 0.0f;
    for (int h = 0; h < HH; h++) p += e4[h] * w2[hp * HE + h * EE + f];
    red[f] = p;
    __syncthreads();
    for (int s = 64; s > 0; s >>= 1) {
      if (f < s) red[f] += red[f + s];
      __syncthreads();
    }
    if (f == 0) {
      float g = red[0];
      if (g < 0.0f) g = AL * g;
      float w = expf(g);
      wrow[(b * HH + hp) * LL + i] = w;
      atomicAdd(&zacc[b * HH + hp], w);
    }
    __syncthreads();
  }
}

// ---- K6: pass 2: recompute rows, accumulate U -----------------------------
__global__ void k_dec(const int* data, const float* Wh, const float* f1,
                      const float* f2, const float* g_enc,
                      const float* b_enc, const float* wrow,
                      float* U) {
  int c = blockIdx.x;
  int b = blockIdx.y;
  int f = threadIdx.x;
  __shared__ float wj[NN];
  __shared__ float red[EE];
  __shared__ float Us[HH * HE];
  for (int k = f; k < HH * HE; k += EE) Us[k] = 0.0f;
  __syncthreads();
  for (int r = 0; r < 32; r++) {
    int i = c * 32 + r;
    if (data[b * LL + i] == 0) continue;   // block-uniform
    float x[HH];
    for (int h = 0; h < HH; h++) {
      float f1i = f1[h * NN + i];
      for (int j = f; j < NN; j += EE) {
        float w = 0.0f;
        if (j < LL) {
          if (data[b * LL + j] != 0) {
            float lg = f1i + f2[h * NN + j];
            if (lg < 0.0f) lg = AL * lg;
            w = expf(lg);
          }
        }
        wj[j] = w;
      }
      __syncthreads();
      float p = 0.0f;
      for (int j = f; j < NN; j += EE) p += wj[j];
      red[f] = p;
      __syncthreads();
      for (int s = 64; s > 0; s >>= 1) {
        if (f < s) red[f] += red[f + s];
        __syncthreads();
      }
      float den = red[0];
      __syncthreads();
      float acc = 0.0f;
      for (int j = 0; j < LL; j++) {
        float w = wj[j];
        if (w != 0.0f) acc += w * Wh[(h * NN + j) * EE + f];
      }
      float v = acc / den;
      x[h] = (v > 0.0f) ? v : (expf(v) - 1.0f);
      __syncthreads();
    }
    red[f] = x[0] + x[1] + x[2] + x[3];
    __syncthreads();
    for (int s = 64; s > 0; s >>= 1) {
      if (f < s) red[f] += red[f + s];
      __syncthreads();
    }
    float mu = red[0] / 512.0f;
    __syncthreads();
    float q = 0.0f;
    for (int h = 0; h < HH; h++) { float d = x[h] - mu; q += d * d; }
    red[f] = q;
    __syncthreads();
    for (int s = 64; s > 0; s >>= 1) {
      if (f < s) red[f] += red[f + s];
      __syncthreads();
    }
    float sd = sqrtf(red[0] / 511.0f);
    float inv = 1.0f / (sd + EPSV);
    __syncthreads();
    for (int h = 0; h < HH; h++) {
      float v = g_enc[h * EE + f] * (x[h] - mu) * inv + b_enc[h * EE + f];
      float e = (v > 0.0f) ? v : (expf(v) - 1.0f);
      for (int hp = 0; hp < HH; hp++) {
        float w = wrow[(b * HH + hp) * LL + i];
        Us[hp * HE + h * EE + f] += w * e;
      }
    }
    __syncthreads();
  }
  for (int k = f; k < HH * HE; k += EE)
    atomicAdd(&U[b * HH * HE + k], Us[k]);
}

// ---- K7: finalize. OUTPUT IS FP32 (root cause of rounds 7-17). ------------
__global__ void k_final(const float* U, const float* zacc,
                        const float* W_dec,
                        const float* g_dec, const float* b_dec,
                        const float* V_w, const float* V_b,
                        const float* o1_w, const float* o1_b,
                        const float* o2_w, const float* o2_b,
                        float* out) {
  int b = blockIdx.x;
  int f = threadIdx.x;
  __shared__ float red[DD];
  __shared__ float xs[DD];
  float dec = 0.0f;
  for (int h = 0; h < HH; h++) {
    float s = 0.0f;
    for (int k = 0; k < HE; k++) {
      s += U[b * HH * HE + h * HE + k] * W_dec[(h * HE + k) * DD + f];
    }
    dec += s / (1.0f + zacc[b * HH + h]);   // +1: row-1024 self term (enc=0)
  }
  dec *= 0.25f;
  red[f] = dec;
  __syncthreads();
  for (int s = 64; s > 0; s >>= 1) {
    if (f < s) red[f] += red[f + s];
    __syncthreads();
  }
  float mu = red[0] / 128.0f;
  __syncthreads();
  float dd = dec - mu;
  red[f] = dd * dd;
  __syncthreads();
  for (int s = 64; s > 0; s >>= 1) {
    if (f < s) red[f] += red[f + s];
    __syncthreads();
  }
  float sd = sqrtf(red[0] / 127.0f);
  float t = g_dec[f] * dd / (sd + EPSV) + b_dec[f];
  if (t < 0.0f) t = 0.0f;
  __syncthreads();
  xs[f] = t;
  __syncthreads();
  float xv = 0.0f;
  for (int k = 0; k < DD; k++) xv += xs[k] * V_w[k * DD + f];
  xv += V_b[f];
  __syncthreads();
  xs[f] = xv;
  __syncthreads();
  float hv = 0.0f;
  for (int k = 0; k < DD; k++) hv += xs[k] * o1_w[k * DD + f];
  hv += o1_b[f];
  if (hv < 0.0f) hv = 0.0f;
  red[f] = hv * o2_w[f];
  __syncthreads();
  for (int s = 64; s > 0; s >>= 1) {
    if (f < s) red[f] += red[f + s];
    __syncthreads();
  }
  if (f == 0) out[b] = red[0] + o2_b[0];
}

extern "C" void kernel_launch(void* const* d_in, const int* in_sizes, int n_in,
                              void* d_out, int out_size, void* d_ws, size_t ws_size,
                              hipStream_t stream) {
  const int* data    = (const int*)d_in[0];
  const float* embed  = (const float*)d_in[1];
  const float* W_enc  = (const float*)d_in[2];
  // DOCUMENTED order restored: R9 forensics (valid under fp32-out model)
  // verified dict order; swap "evidence" (R14) was a mispairing artifact.
  const float* a_esrc = (const float*)d_in[3];
  const float* a_edst = (const float*)d_in[4];
  const float* g_enc  = (const float*)d_in[5];
  const float* b_enc  = (const float*)d_in[6];
  const float* W_dec  = (const float*)d_in[7];
  const float* a_ddst = (const float*)d_in[9];
  const float* g_dec  = (const float*)d_in[10];
  const float* b_dec  = (const float*)d_in[11];
  const float* V_w    = (const float*)d_in[12];
  const float* V_b    = (const float*)d_in[13];
  const float* o1_w   = (const float*)d_in[14];
  const float* o1_b   = (const float*)d_in[15];
  const float* o2_w   = (const float*)d_in[16];
  const float* o2_b   = (const float*)d_in[17];
  float* out = (float*)d_out;               // fp32 output

  float* w = (float*)d_ws;
  float* Wh   = w + O_WH;
  float* f1   = w + O_F1;
  float* f2   = w + O_F2;
  float* w2   = w + O_W2;
  float* wrow = w + O_WR;
  float* zacc = w + O_Z;
  float* U    = w + O_U;

  VGNN_27049704030896_kernel<<<dim3(NN, HH), 128, 0, stream>>>(embed, W_enc, Wh);
  k_f12 <<<dim3(NN, HH), 128, 0, stream>>>(Wh, a_esrc, a_edst, f1, f2);
  k_w2  <<<dim3(HE / 128, HH), 128, 0, stream>>>(W_dec, a_ddst, w2);
  k_zero<<<(BB * HH * HE + 255) / 256, 256, 0, stream>>>(U, zacc);
  k_enc <<<dim3(LL, BB), 128, 0, stream>>>(data, Wh, f1, f2, g_enc, b_enc, w2, wrow, zacc);
  k_dec <<<dim3(LL / 32, BB), 128, 0, stream>>>(data, Wh, f1, f2, g_enc, b_enc, wrow, U);
  k_final<<<BB, 128, 0, stream>>>(U, zacc, W_dec, g_dec, b_dec, V_w, V_b,
                                  o1_w, o1_b, o2_w, o2_b, out);
}

// Round 19
// 482.563 us; speedup vs baseline: 21.6863x; 21.6863x over previous
//
#include <hip/hip_runtime.h>
#include <hip/hip_bf16.h>

#define BB 16
#define LL 1024
#define EE 128
#define HH 4
#define DD 128
#define NN 1025
#define HE 512
#define AL 0.2f
#define EPSV 1e-6f
#define SS 8
#define CC 128
#define C1 129

// workspace float offsets (total 6,986,440 floats = 27.9 MB; ws >= 36.3 MB verified R9)
#define O_WH   0
#define O_F1   524800
#define O_F2   528900
#define O_F2S  533000
#define O_ELO  537096
#define O_EHI  541192
#define O_EF1H 545288
#define O_EF1L 549384
#define O_W2   553480
#define O_SLO  555528
#define O_SHI  1612296
#define O_SLOS 2669064
#define O_SHIS 2677320
#define O_WR   2685576
#define O_Z    2751112
#define O_U    2751176
#define O_JS   2783944
#define O_PS   2788040
#define O_E4   2792136

// ---- K1: Wh[h,n,f] = sum_e emb[n,e] * W_enc[h,e,f]  (emb row 0 = 0) --------
__global__ void VGNN_27049704030896_kernel(const float* embed,
                                           const float* W_enc,
                                           float* Wh) {
  int n = blockIdx.x;
  int h = blockIdx.y;
  int f = threadIdx.x;
  float acc = 0.0f;
  if (n > 0) {
    for (int e = 0; e < EE; e++) {
      acc += embed[n * EE + e] * W_enc[(h * EE + e) * EE + f];
    }
  }
  Wh[(h * NN + n) * EE + f] = acc;
}

// ---- K2: f1/f2 row dots + exp(f1) tables ----------------------------------
__global__ void k_f12(const float* Wh, const float* a_src,
                      const float* a_dst, float* f1, float* f2,
                      float* ef1hi, float* ef1lo) {
  __shared__ float r1[EE];
  __shared__ float r2[EE];
  int n = blockIdx.x;
  int h = blockIdx.y;
  int f = threadIdx.x;
  float w = Wh[(h * NN + n) * EE + f];
  r1[f] = w * a_src[h * EE + f];
  r2[f] = w * a_dst[h * EE + f];
  __syncthreads();
  for (int s = 64; s > 0; s >>= 1) {
    if (f < s) { r1[f] += r1[f + s]; r2[f] += r2[f + s]; }
    __syncthreads();
  }
  if (f == 0) {
    f1[h * NN + n] = r1[0];
    f2[h * NN + n] = r2[0];
    if (n < LL) {
      ef1hi[h * LL + n] = expf(r1[0]);
      ef1lo[h * LL + n] = expf(AL * r1[0]);
    }
  }
}

// ---- K3: bitonic sort f2[h, 0..L) ascending + sorted exp tables -----------
__global__ void k_sort(const float* f2, float* f2s, int* jsort,
                       float* elo, float* ehi) {
  __shared__ float key[LL];
  __shared__ int idx[LL];
  int h = blockIdx.x;
  int t = threadIdx.x;   // 512 threads
  key[t] = f2[h * NN + t];             idx[t] = t;
  key[t + 512] = f2[h * NN + t + 512]; idx[t + 512] = t + 512;
  for (int k = 2; k <= LL; k <<= 1) {
    for (int j = k >> 1; j > 0; j >>= 1) {
      __syncthreads();
      int i = ((t / j) * (j * 2)) + (t % j);
      int p = i + j;
      int up = ((i & k) == 0) ? 1 : 0;
      float a = key[i];
      float b2 = key[p];
      int sw = 0;
      if (up == 1) { if (a > b2) sw = 1; }
      else { if (a < b2) sw = 1; }
      if (sw == 1) {
        key[i] = b2; key[p] = a;
        int tm = idx[i]; idx[i] = idx[p]; idx[p] = tm;
      }
    }
  }
  __syncthreads();
  for (int q = t; q < LL; q += 512) {
    float kv = key[q];
    f2s[h * LL + q] = kv;
    jsort[h * LL + q] = idx[q];
    elo[h * LL + q] = expf(AL * kv);
    ehi[h * LL + q] = expf(kv);
  }
}

// ---- K4: pstar[h,i] = lower_bound(f2s[h], -f1[h,i]) -----------------------
__global__ void k_pstar(const float* f2s, const float* f1, int* pstar) {
  __shared__ float ks[LL];
  int h = blockIdx.y;
  int i = blockIdx.x * 256 + threadIdx.x;
  for (int q = threadIdx.x; q < LL; q += 256) ks[q] = f2s[h * LL + q];
  __syncthreads();
  float t = -f1[h * NN + i];
  int lo = 0;
  int hi = LL;
  while (lo < hi) {
    int m = (lo + hi) >> 1;
    if (ks[m] < t) lo = m + 1; else hi = m;
  }
  pstar[h * LL + i] = lo;
}

// ---- K5a: per-chunk masked weighted totals into snapshot slots ------------
__global__ void k_scanA(const int* data, const int* jsort, const float* elo,
                        const float* ehi, const float* Wh,
                        float* SnapLo, float* SnapHi,
                        float* SnapLoS, float* SnapHiS) {
  int c = blockIdx.x;
  int h = blockIdx.y;
  int b = blockIdx.z;
  int f = threadIdx.x;
  int bh = b * HH + h;
  float alo = 0.0f; float ahi = 0.0f; float slo = 0.0f; float shi = 0.0f;
  for (int r = 0; r < SS; r++) {
    int p = c * SS + r;
    int j = jsort[h * LL + p];
    if (data[b * LL + j] != 0) {
      float wl = elo[h * LL + p];
      float wh2 = ehi[h * LL + p];
      float v = Wh[(h * NN + j) * EE + f];
      alo += wl * v; ahi += wh2 * v; slo += wl; shi += wh2;
    }
  }
  int o = bh * C1 + c;
  SnapLo[(long)o * EE + f] = alo;
  SnapHi[(long)o * EE + f] = ahi;
  if (f == 0) { SnapLoS[o] = slo; SnapHiS[o] = shi; }
}

// ---- K5b: in-place exclusive scan of snapshots; total at slot CC ----------
__global__ void k_scanB(float* SnapLo, float* SnapHi,
                        float* SnapLoS, float* SnapHiS) {
  int bh = blockIdx.x;
  int f = threadIdx.x;
  float rl = 0.0f; float rh = 0.0f; float rls = 0.0f; float rhs = 0.0f;
  for (int c = 0; c < CC; c++) {
    int o = bh * C1 + c;
    float tl = SnapLo[(long)o * EE + f];
    float th = SnapHi[(long)o * EE + f];
    SnapLo[(long)o * EE + f] = rl;
    SnapHi[(long)o * EE + f] = rh;
    rl += tl; rh += th;
    if (f == 0) {
      float sl = SnapLoS[o]; float sh = SnapHiS[o];
      SnapLoS[o] = rls; SnapHiS[o] = rhs;
      rls += sl; rhs += sh;
    }
  }
  int o = bh * C1 + CC;
  SnapLo[(long)o * EE + f] = rl;
  SnapHi[(long)o * EE + f] = rh;
  if (f == 0) { SnapLoS[o] = rls; SnapHiS[o] = rhs; }
}

// ---- K6: w2[h,k] = sum_d W_dec[h,k,d] * a_dec_dst[h,d] --------------------
__global__ void k_w2(const float* W_dec, const float* a_vec, float* w2) {
  int k = blockIdx.x * 128 + threadIdx.x;
  int h = blockIdx.y;
  float s = 0.0f;
  for (int d = 0; d < DD; d++) {
    s += W_dec[(h * HE + k) * DD + d] * a_vec[h * DD + d];
  }
  w2[h * HE + k] = s;
}

// ---- K7: zero U and zacc --------------------------------------------------
__global__ void k_zero(float* U, float* z) {
  int t = blockIdx.x * 256 + threadIdx.x;
  if (t < BB * HH * HE) U[t] = 0.0f;
  if (t < BB * HH) z[t] = 0.0f;
}

// ---- K8: pass 1 per row: prefix-attn -> LN -> elu -> e4(bf16), g2 -> w,z --
__global__ void k_row(const int* data, const float* Wh, const int* pstar,
                      const int* jsort, const float* elo, const float* ehi,
                      const float* ef1hi, const float* ef1lo,
                      const float* SnapLo, const float* SnapHi,
                      const float* SnapLoS, const float* SnapHiS,
                      const float* g_enc, const float* b_enc, const float* w2,
                      __hip_bfloat16* enc4, float* wrow, float* zacc) {
  int i = blockIdx.x;
  int b = blockIdx.y;
  int f = threadIdx.x;
  if (data[b * LL + i] == 0) return;   // block-uniform
  __shared__ float red[EE];
  float x[HH];
  for (int h = 0; h < HH; h++) {
    int p = pstar[h * LL + i];
    int c = p / SS;
    int bh = b * HH + h;
    int o = bh * C1 + c;
    float rl = SnapLo[(long)o * EE + f];
    float rh = SnapHi[(long)o * EE + f];
    float rls = SnapLoS[o];
    float rhs = SnapHiS[o];
    for (int q = c * SS; q < p; q++) {
      int j = jsort[h * LL + q];
      if (data[b * LL + j] != 0) {
        float wl = elo[h * LL + q];
        float wh2 = ehi[h * LL + q];
        float v = Wh[(h * NN + j) * EE + f];
        rl += wl * v; rh += wh2 * v; rls += wl; rhs += wh2;
      }
    }
    int ot = bh * C1 + CC;
    float Th = SnapHi[(long)ot * EE + f];
    float Ths = SnapHiS[ot];
    float eh = ef1hi[h * LL + i];
    float el = ef1lo[h * LL + i];
    float num = eh * (Th - rh) + el * rl;
    float den = eh * (Ths - rhs) + el * rls;
    float v = num / den;
    x[h] = (v > 0.0f) ? v : (expf(v) - 1.0f);
  }
  red[f] = x[0] + x[1] + x[2] + x[3];
  __syncthreads();
  for (int s = 64; s > 0; s >>= 1) {
    if (f < s) red[f] += red[f + s];
    __syncthreads();
  }
  float mu = red[0] / 512.0f;
  __syncthreads();
  float q2 = 0.0f;
  for (int h = 0; h < HH; h++) { float d = x[h] - mu; q2 += d * d; }
  red[f] = q2;
  __syncthreads();
  for (int s = 64; s > 0; s >>= 1) {
    if (f < s) red[f] += red[f + s];
    __syncthreads();
  }
  float sd = sqrtf(red[0] / 511.0f);
  float inv = 1.0f / (sd + EPSV);
  __syncthreads();
  float e4[HH];
  for (int h = 0; h < HH; h++) {
    float v = g_enc[h * EE + f] * (x[h] - mu) * inv + b_enc[h * EE + f];
    e4[h] = (v > 0.0f) ? v : (expf(v) - 1.0f);
    enc4[((long)(b * LL + i)) * HE + h * EE + f] = __float2bfloat16(e4[h]);
  }
  for (int hp = 0; hp < HH; hp++) {
    float p = 0.0f;
    for (int h = 0; h < HH; h++) p += e4[h] * w2[hp * HE + h * EE + f];
    red[f] = p;
    __syncthreads();
    for (int s = 64; s > 0; s >>= 1) {
      if (f < s) red[f] += red[f + s];
      __syncthreads();
    }
    if (f == 0) {
      float g = red[0];
      if (g < 0.0f) g = AL * g;
      float w = expf(g);
      wrow[(b * HH + hp) * LL + i] = w;
      atomicAdd(&zacc[b * HH + hp], w);
    }
    __syncthreads();
  }
}

// ---- K9: pass 2: stream e4 rows, accumulate U -----------------------------
__global__ void k_acc(const int* data, const __hip_bfloat16* enc4,
                      const float* wrow, float* U) {
  __shared__ float Us[HH * HE];
  int c = blockIdx.x;
  int b = blockIdx.y;
  int f = threadIdx.x;
  for (int k = f; k < HH * HE; k += EE) Us[k] = 0.0f;
  __syncthreads();
  for (int r = 0; r < 32; r++) {
    int i = c * 32 + r;
    if (data[b * LL + i] == 0) continue;
    float w0 = wrow[(b * HH + 0) * LL + i];
    float w1 = wrow[(b * HH + 1) * LL + i];
    float w2v = wrow[(b * HH + 2) * LL + i];
    float w3 = wrow[(b * HH + 3) * LL + i];
    for (int m = 0; m < 4; m++) {
      float e = __bfloat162float(enc4[((long)(b * LL + i)) * HE + m * EE + f]);
      Us[0 * HE + m * EE + f] += w0 * e;
      Us[1 * HE + m * EE + f] += w1 * e;
      Us[2 * HE + m * EE + f] += w2v * e;
      Us[3 * HE + m * EE + f] += w3 * e;
    }
  }
  __syncthreads();
  for (int k = f; k < HH * HE; k += EE)
    atomicAdd(&U[b * HH * HE + k], Us[k]);
}

// ---- K10: finalize (fp32 output) ------------------------------------------
__global__ void k_final(const float* U, const float* zacc,
                        const float* W_dec,
                        const float* g_dec, const float* b_dec,
                        const float* V_w, const float* V_b,
                        const float* o1_w, const float* o1_b,
                        const float* o2_w, const float* o2_b,
                        float* out) {
  __shared__ float Us[HH * HE];
  __shared__ float red[DD];
  __shared__ float xs[DD];
  int b = blockIdx.x;
  int f = threadIdx.x;
  for (int k = f; k < HH * HE; k += DD) Us[k] = U[b * HH * HE + k];
  __syncthreads();
  float dec = 0.0f;
  for (int h = 0; h < HH; h++) {
    float s = 0.0f;
    for (int k = 0; k < HE; k++) {
      s += Us[h * HE + k] * W_dec[(h * HE + k) * DD + f];
    }
    dec += s / (1.0f + zacc[b * HH + h]);   // +1: row-1024 self term (enc=0)
  }
  dec *= 0.25f;
  red[f] = dec;
  __syncthreads();
  for (int s = 64; s > 0; s >>= 1) {
    if (f < s) red[f] += red[f + s];
    __syncthreads();
  }
  float mu = red[0] / 128.0f;
  __syncthreads();
  float dd = dec - mu;
  red[f] = dd * dd;
  __syncthreads();
  for (int s = 64; s > 0; s >>= 1) {
    if (f < s) red[f] += red[f + s];
    __syncthreads();
  }
  float sd = sqrtf(red[0] / 127.0f);
  float t = g_dec[f] * dd / (sd + EPSV) + b_dec[f];
  if (t < 0.0f) t = 0.0f;
  __syncthreads();
  xs[f] = t;
  __syncthreads();
  float xv = 0.0f;
  for (int k = 0; k < DD; k++) xv += xs[k] * V_w[k * DD + f];
  xv += V_b[f];
  __syncthreads();
  xs[f] = xv;
  __syncthreads();
  float hv = 0.0f;
  for (int k = 0; k < DD; k++) hv += xs[k] * o1_w[k * DD + f];
  hv += o1_b[f];
  if (hv < 0.0f) hv = 0.0f;
  red[f] = hv * o2_w[f];
  __syncthreads();
  for (int s = 64; s > 0; s >>= 1) {
    if (f < s) red[f] += red[f + s];
    __syncthreads();
  }
  if (f == 0) out[b] = red[0] + o2_b[0];
}

extern "C" void kernel_launch(void* const* d_in, const int* in_sizes, int n_in,
                              void* d_out, int out_size, void* d_ws, size_t ws_size,
                              hipStream_t stream) {
  const int* data    = (const int*)d_in[0];
  const float* embed  = (const float*)d_in[1];
  const float* W_enc  = (const float*)d_in[2];
  const float* a_esrc = (const float*)d_in[3];
  const float* a_edst = (const float*)d_in[4];
  const float* g_enc  = (const float*)d_in[5];
  const float* b_enc  = (const float*)d_in[6];
  const float* W_dec  = (const float*)d_in[7];
  const float* a_ddst = (const float*)d_in[9];
  const float* g_dec  = (const float*)d_in[10];
  const float* b_dec  = (const float*)d_in[11];
  const float* V_w    = (const float*)d_in[12];
  const float* V_b    = (const float*)d_in[13];
  const float* o1_w   = (const float*)d_in[14];
  const float* o1_b   = (const float*)d_in[15];
  const float* o2_w   = (const float*)d_in[16];
  const float* o2_b   = (const float*)d_in[17];
  float* out = (float*)d_out;               // fp32 output (root cause R0-R17)

  float* w = (float*)d_ws;
  float* Wh    = w + O_WH;
  float* f1    = w + O_F1;
  float* f2    = w + O_F2;
  float* f2s   = w + O_F2S;
  float* elo   = w + O_ELO;
  float* ehi   = w + O_EHI;
  float* ef1hi = w + O_EF1H;
  float* ef1lo = w + O_EF1L;
  float* w2    = w + O_W2;
  float* SnapLo  = w + O_SLO;
  float* SnapHi  = w + O_SHI;
  float* SnapLoS = w + O_SLOS;
  float* SnapHiS = w + O_SHIS;
  float* wrow  = w + O_WR;
  float* zacc  = w + O_Z;
  float* U     = w + O_U;
  int* jsort   = (int*)(w + O_JS);
  int* pstar   = (int*)(w + O_PS);
  __hip_bfloat16* enc4 = (__hip_bfloat16*)(w + O_E4);

  VGNN_27049704030896_kernel<<<dim3(NN, HH), 128, 0, stream>>>(embed, W_enc, Wh);
  k_f12 <<<dim3(NN, HH), 128, 0, stream>>>(Wh, a_esrc, a_edst, f1, f2, ef1hi, ef1lo);
  k_sort<<<HH, 512, 0, stream>>>(f2, f2s, jsort, elo, ehi);
  k_pstar<<<dim3(LL / 256, HH), 256, 0, stream>>>(f2s, f1, pstar);
  k_scanA<<<dim3(CC, HH, BB), 128, 0, stream>>>(data, jsort, elo, ehi, Wh,
                                                SnapLo, SnapHi, SnapLoS, SnapHiS);
  k_scanB<<<BB * HH, 128, 0, stream>>>(SnapLo, SnapHi, SnapLoS, SnapHiS);
  k_w2  <<<dim3(HE / 128, HH), 128, 0, stream>>>(W_dec, a_ddst, w2);
  k_zero<<<(BB * HH * HE + 255) / 256, 256, 0, stream>>>(U, zacc);
  k_row <<<dim3(LL, BB), 128, 0, stream>>>(data, Wh, pstar, jsort, elo, ehi,
                                           ef1hi, ef1lo, SnapLo, SnapHi,
                                           SnapLoS, SnapHiS, g_enc, b_enc, w2,
                                           enc4, wrow, zacc);
  k_acc <<<dim3(LL / 32, BB), 128, 0, stream>>>(data, enc4, wrow, U);
  k_final<<<BB, 128, 0, stream>>>(U, zacc, W_dec, g_dec, b_dec, V_w, V_b,
                                  o1_w, o1_b, o2_w, o2_b, out);
}

// Round 20
// 298.557 us; speedup vs baseline: 35.0520x; 1.6163x over previous
//
#include <hip/hip_runtime.h>
#include <hip/hip_bf16.h>

#define BB 16
#define LL 1024
#define EE 128
#define HH 4
#define DD 128
#define NN 1025
#define HE 512
#define AL 0.2f
#define EPSV 1e-6f
#define SS 8
#define CC 128
#define C1 129

// workspace float offsets (total ~8.0M floats = 32.0 MB; ws >= 36.3 MB verified R9)
#define O_WH   0
#define O_F1   524800
#define O_F2   528900
#define O_F2S  533000
#define O_ELO  537096
#define O_EHI  541192
#define O_EF1H 545288
#define O_EF1L 549384
#define O_W2   553480
#define O_SLO  555528
#define O_SHI  1612296
#define O_SLOS 2669064
#define O_SHIS 2677320
#define O_WR   2685576
#define O_UP   2751112
#define O_JS   3799688
#define O_PS   3803784
#define O_E4   3807880

// ---- K1: Wh + f1/f2 + exp tables (fused) -----------------------------------
__global__ void VGNN_27049704030896_kernel(const float* embed, const float* W_enc,
                                           const float* a_src, const float* a_dst,
                                           float* Wh, float* f1, float* f2,
                                           float* ef1hi, float* ef1lo) {
  __shared__ float r1[EE];
  __shared__ float r2[EE];
  int n = blockIdx.x;
  int h = blockIdx.y;
  int f = threadIdx.x;
  float acc = 0.0f;
  if (n > 0) {
    for (int e = 0; e < EE; e++) {
      acc += embed[n * EE + e] * W_enc[(h * EE + e) * EE + f];
    }
  }
  Wh[(h * NN + n) * EE + f] = acc;
  r1[f] = acc * a_src[h * EE + f];
  r2[f] = acc * a_dst[h * EE + f];
  __syncthreads();
  for (int s = 64; s > 0; s >>= 1) {
    if (f < s) { r1[f] += r1[f + s]; r2[f] += r2[f + s]; }
    __syncthreads();
  }
  if (f == 0) {
    f1[h * NN + n] = r1[0];
    f2[h * NN + n] = r2[0];
    if (n < LL) {
      ef1hi[h * LL + n] = expf(r1[0]);
      ef1lo[h * LL + n] = expf(AL * r1[0]);
    }
  }
}

// ---- K2: bitonic sort + exp tables + pstar binary search (fused) ----------
__global__ void k_sortp(const float* f2, const float* f1,
                        float* f2s, int* jsort, float* elo, float* ehi,
                        int* pstar) {
  __shared__ float key[LL];
  __shared__ int idx[LL];
  int h = blockIdx.x;
  int t = threadIdx.x;   // 512 threads
  key[t] = f2[h * NN + t];             idx[t] = t;
  key[t + 512] = f2[h * NN + t + 512]; idx[t + 512] = t + 512;
  for (int k = 2; k <= LL; k <<= 1) {
    for (int j = k >> 1; j > 0; j >>= 1) {
      __syncthreads();
      int i = ((t / j) * (j * 2)) + (t % j);
      int p = i + j;
      int up = ((i & k) == 0) ? 1 : 0;
      float a = key[i];
      float b2 = key[p];
      int sw = 0;
      if (up == 1) { if (a > b2) sw = 1; }
      else { if (a < b2) sw = 1; }
      if (sw == 1) {
        key[i] = b2; key[p] = a;
        int tm = idx[i]; idx[i] = idx[p]; idx[p] = tm;
      }
    }
  }
  __syncthreads();
  for (int q = t; q < LL; q += 512) {
    float kv = key[q];
    f2s[h * LL + q] = kv;
    jsort[h * LL + q] = idx[q];
    elo[h * LL + q] = expf(AL * kv);
    ehi[h * LL + q] = expf(kv);
  }
  // pstar via binary search over sorted keys still in LDS
  for (int q = t; q < LL; q += 512) {
    float tg = -f1[h * NN + q];
    int lo = 0;
    int hi = LL;
    while (lo < hi) {
      int m = (lo + hi) >> 1;
      if (key[m] < tg) lo = m + 1; else hi = m;
    }
    pstar[h * LL + q] = lo;
  }
}

// ---- K3: per-chunk masked weighted totals into snapshot slots -------------
__global__ void k_scanA(const int* data, const int* jsort, const float* elo,
                        const float* ehi, const float* Wh,
                        float* SnapLo, float* SnapHi,
                        float* SnapLoS, float* SnapHiS) {
  int c = blockIdx.x;
  int h = blockIdx.y;
  int b = blockIdx.z;
  int f = threadIdx.x;
  int bh = b * HH + h;
  float alo = 0.0f; float ahi = 0.0f; float slo = 0.0f; float shi = 0.0f;
  for (int r = 0; r < SS; r++) {
    int p = c * SS + r;
    int j = jsort[h * LL + p];
    if (data[b * LL + j] != 0) {
      float wl = elo[h * LL + p];
      float wh2 = ehi[h * LL + p];
      float v = Wh[(h * NN + j) * EE + f];
      alo += wl * v; ahi += wh2 * v; slo += wl; shi += wh2;
    }
  }
  int o = bh * C1 + c;
  SnapLo[(long)o * EE + f] = alo;
  SnapHi[(long)o * EE + f] = ahi;
  if (f == 0) { SnapLoS[o] = slo; SnapHiS[o] = shi; }
}

// ---- K4: in-place exclusive scan of snapshots; total at slot CC -----------
__global__ void k_scanB(float* SnapLo, float* SnapHi,
                        float* SnapLoS, float* SnapHiS) {
  int bh = blockIdx.x;
  int f = threadIdx.x;
  float rl = 0.0f; float rh = 0.0f; float rls = 0.0f; float rhs = 0.0f;
  for (int c = 0; c < CC; c++) {
    int o = bh * C1 + c;
    float tl = SnapLo[(long)o * EE + f];
    float th = SnapHi[(long)o * EE + f];
    SnapLo[(long)o * EE + f] = rl;
    SnapHi[(long)o * EE + f] = rh;
    rl += tl; rh += th;
    if (f == 0) {
      float sl = SnapLoS[o]; float sh = SnapHiS[o];
      SnapLoS[o] = rls; SnapHiS[o] = rhs;
      rls += sl; rhs += sh;
    }
  }
  int o = bh * C1 + CC;
  SnapLo[(long)o * EE + f] = rl;
  SnapHi[(long)o * EE + f] = rh;
  if (f == 0) { SnapLoS[o] = rls; SnapHiS[o] = rhs; }
}

// ---- K5: w2[h,k] = sum_d W_dec[h,k,d] * a_dec_dst[h,d] --------------------
__global__ void k_w2(const float* W_dec, const float* a_vec, float* w2) {
  int k = blockIdx.x * 128 + threadIdx.x;
  int h = blockIdx.y;
  float s = 0.0f;
  for (int d = 0; d < DD; d++) {
    s += W_dec[(h * HE + k) * DD + d] * a_vec[h * DD + d];
  }
  w2[h * HE + k] = s;
}

// ---- K6: wave-per-row: prefix-attn -> LN -> elu -> e4(bf16), g2 -> wrow ---
__global__ void k_row(const int* data, const float* Wh, const int* pstar,
                      const int* jsort, const float* elo, const float* ehi,
                      const float* ef1hi, const float* ef1lo,
                      const float* SnapLo, const float* SnapHi,
                      const float* SnapLoS, const float* SnapHiS,
                      const float* g_enc, const float* b_enc, const float* w2,
                      __hip_bfloat16* enc4, float* wrow) {
  int i = blockIdx.x;
  int b = blockIdx.y;
  int t = threadIdx.x;   // 64 threads = 1 wave; features t and t+64
  if (data[b * LL + i] == 0) {
    if (t < HH) wrow[(b * HH + t) * LL + i] = 0.0f;   // keep k_final sums clean
    return;
  }
  __shared__ float red[64];
  __shared__ float red4[HH][64];
  float x0[HH];
  float x1[HH];
  for (int h = 0; h < HH; h++) {
    int p = pstar[h * LL + i];
    int c = p / SS;
    int bh = b * HH + h;
    int o = bh * C1 + c;
    float rl0 = SnapLo[(long)o * EE + t];
    float rl1 = SnapLo[(long)o * EE + t + 64];
    float rh0 = SnapHi[(long)o * EE + t];
    float rh1 = SnapHi[(long)o * EE + t + 64];
    float rls = SnapLoS[o];
    float rhs = SnapHiS[o];
    int q0 = c * SS;
    int np = p - q0;                 // 0..7, wave-uniform
#pragma unroll
    for (int r = 0; r < 7; r++) {
      if (r < np) {
        int j = jsort[h * LL + q0 + r];
        if (data[b * LL + j] != 0) {
          float wl = elo[h * LL + q0 + r];
          float wh2 = ehi[h * LL + q0 + r];
          float v0 = Wh[(h * NN + j) * EE + t];
          float v1 = Wh[(h * NN + j) * EE + t + 64];
          rl0 += wl * v0; rl1 += wl * v1;
          rh0 += wh2 * v0; rh1 += wh2 * v1;
          rls += wl; rhs += wh2;
        }
      }
    }
    int ot = bh * C1 + CC;
    float Th0 = SnapHi[(long)ot * EE + t];
    float Th1 = SnapHi[(long)ot * EE + t + 64];
    float Ths = SnapHiS[ot];
    float eh = ef1hi[h * LL + i];
    float el = ef1lo[h * LL + i];
    float den = eh * (Ths - rhs) + el * rls;
    float v0 = (eh * (Th0 - rh0) + el * rl0) / den;
    float v1 = (eh * (Th1 - rh1) + el * rl1) / den;
    x0[h] = (v0 > 0.0f) ? v0 : (expf(v0) - 1.0f);
    x1[h] = (v1 > 0.0f) ? v1 : (expf(v1) - 1.0f);
  }
  // LN over 512 (single-wave trees: barriers are free)
  float loc = 0.0f;
  for (int h = 0; h < HH; h++) loc += x0[h] + x1[h];
  red[t] = loc;
  __syncthreads();
  for (int s = 32; s > 0; s >>= 1) {
    if (t < s) red[t] += red[t + s];
    __syncthreads();
  }
  float mu = red[0] / 512.0f;
  __syncthreads();
  float q2 = 0.0f;
  for (int h = 0; h < HH; h++) {
    float d0 = x0[h] - mu; float d1 = x1[h] - mu;
    q2 += d0 * d0 + d1 * d1;
  }
  red[t] = q2;
  __syncthreads();
  for (int s = 32; s > 0; s >>= 1) {
    if (t < s) red[t] += red[t + s];
    __syncthreads();
  }
  float sd = sqrtf(red[0] / 511.0f);
  float inv = 1.0f / (sd + EPSV);
  float e40[HH];
  float e41[HH];
  long rowo = ((long)(b * LL + i)) * HE;
  for (int h = 0; h < HH; h++) {
    float v0 = g_enc[h * EE + t] * (x0[h] - mu) * inv + b_enc[h * EE + t];
    float v1 = g_enc[h * EE + t + 64] * (x1[h] - mu) * inv + b_enc[h * EE + t + 64];
    e40[h] = (v0 > 0.0f) ? v0 : (expf(v0) - 1.0f);
    e41[h] = (v1 > 0.0f) ? v1 : (expf(v1) - 1.0f);
    enc4[rowo + h * EE + t] = __float2bfloat16(e40[h]);
    enc4[rowo + h * EE + t + 64] = __float2bfloat16(e41[h]);
  }
  // 4 g2 dot-products reduced in one tree (ILP)
  for (int hp = 0; hp < HH; hp++) {
    float p = 0.0f;
    for (int h = 0; h < HH; h++) {
      p += e40[h] * w2[hp * HE + h * EE + t];
      p += e41[h] * w2[hp * HE + h * EE + t + 64];
    }
    red4[hp][t] = p;
  }
  __syncthreads();
  for (int s = 32; s > 0; s >>= 1) {
    if (t < s) {
      red4[0][t] += red4[0][t + s];
      red4[1][t] += red4[1][t + s];
      red4[2][t] += red4[2][t + s];
      red4[3][t] += red4[3][t + s];
    }
    __syncthreads();
  }
  if (t < HH) {
    float g = red4[t][0];
    if (g < 0.0f) g = AL * g;
    wrow[(b * HH + t) * LL + i] = expf(g);
  }
}

// ---- K7: stream e4 rows, write per-chunk U partials (no atomics) ----------
__global__ void k_acc(const int* data, const __hip_bfloat16* enc4,
                      const float* wrow, float* Upart) {
  __shared__ float Us[HH * HE];
  int c = blockIdx.x;
  int b = blockIdx.y;
  int f = threadIdx.x;
  for (int k = f; k < HH * HE; k += EE) Us[k] = 0.0f;
  __syncthreads();
  for (int r = 0; r < 32; r++) {
    int i = c * 32 + r;
    if (data[b * LL + i] == 0) continue;
    float w0 = wrow[(b * HH + 0) * LL + i];
    float w1 = wrow[(b * HH + 1) * LL + i];
    float w2v = wrow[(b * HH + 2) * LL + i];
    float w3 = wrow[(b * HH + 3) * LL + i];
    for (int m = 0; m < 4; m++) {
      float e = __bfloat162float(enc4[((long)(b * LL + i)) * HE + m * EE + f]);
      Us[0 * HE + m * EE + f] += w0 * e;
      Us[1 * HE + m * EE + f] += w1 * e;
      Us[2 * HE + m * EE + f] += w2v * e;
      Us[3 * HE + m * EE + f] += w3 * e;
    }
  }
  __syncthreads();
  long base = (long)(b * 32 + c) * (HH * HE);
  for (int k = f; k < HH * HE; k += EE) Upart[base + k] = Us[k];
}

// ---- K8: finalize: sum partials, zacc from wrow, dec, LN, MLP (fp32 out) --
__global__ void k_final(const float* Upart, const float* wrow,
                        const float* W_dec,
                        const float* g_dec, const float* b_dec,
                        const float* V_w, const float* V_b,
                        const float* o1_w, const float* o1_b,
                        const float* o2_w, const float* o2_b,
                        float* out) {
  __shared__ float Us[HH * HE];
  __shared__ float zL[HH];
  __shared__ float red[DD];
  __shared__ float xs[DD];
  int b = blockIdx.x;
  int f = threadIdx.x;   // 128
  for (int k = f; k < HH * HE; k += DD) {
    float s = 0.0f;
    for (int c = 0; c < 32; c++) {
      s += Upart[(long)(b * 32 + c) * (HH * HE) + k];
    }
    Us[k] = s;
  }
  for (int hp = 0; hp < HH; hp++) {
    float p = 0.0f;
    for (int q = f; q < LL; q += DD) p += wrow[(b * HH + hp) * LL + q];
    red[f] = p;
    __syncthreads();
    for (int s = 64; s > 0; s >>= 1) {
      if (f < s) red[f] += red[f + s];
      __syncthreads();
    }
    if (f == 0) zL[hp] = red[0];
    __syncthreads();
  }
  float dec = 0.0f;
  for (int h = 0; h < HH; h++) {
    float s = 0.0f;
    for (int k = 0; k < HE; k++) {
      s += Us[h * HE + k] * W_dec[(h * HE + k) * DD + f];
    }
    dec += s / (1.0f + zL[h]);   // +1: row-1024 self term (enc=0)
  }
  dec *= 0.25f;
  red[f] = dec;
  __syncthreads();
  for (int s = 64; s > 0; s >>= 1) {
    if (f < s) red[f] += red[f + s];
    __syncthreads();
  }
  float mu = red[0] / 128.0f;
  __syncthreads();
  float dd = dec - mu;
  red[f] = dd * dd;
  __syncthreads();
  for (int s = 64; s > 0; s >>= 1) {
    if (f < s) red[f] += red[f + s];
    __syncthreads();
  }
  float sd = sqrtf(red[0] / 127.0f);
  float t = g_dec[f] * dd / (sd + EPSV) + b_dec[f];
  if (t < 0.0f) t = 0.0f;
  __syncthreads();
  xs[f] = t;
  __syncthreads();
  float xv = 0.0f;
  for (int k = 0; k < DD; k++) xv += xs[k] * V_w[k * DD + f];
  xv += V_b[f];
  __syncthreads();
  xs[f] = xv;
  __syncthreads();
  float hv = 0.0f;
  for (int k = 0; k < DD; k++) hv += xs[k] * o1_w[k * DD + f];
  hv += o1_b[f];
  if (hv < 0.0f) hv = 0.0f;
  red[f] = hv * o2_w[f];
  __syncthreads();
  for (int s = 64; s > 0; s >>= 1) {
    if (f < s) red[f] += red[f + s];
    __syncthreads();
  }
  if (f == 0) out[b] = red[0] + o2_b[0];
}

extern "C" void kernel_launch(void* const* d_in, const int* in_sizes, int n_in,
                              void* d_out, int out_size, void* d_ws, size_t ws_size,
                              hipStream_t stream) {
  const int* data    = (const int*)d_in[0];
  const float* embed  = (const float*)d_in[1];
  const float* W_enc  = (const float*)d_in[2];
  const float* a_esrc = (const float*)d_in[3];
  const float* a_edst = (const float*)d_in[4];
  const float* g_enc  = (const float*)d_in[5];
  const float* b_enc  = (const float*)d_in[6];
  const float* W_dec  = (const float*)d_in[7];
  const float* a_ddst = (const float*)d_in[9];
  const float* g_dec  = (const float*)d_in[10];
  const float* b_dec  = (const float*)d_in[11];
  const float* V_w    = (const float*)d_in[12];
  const float* V_b    = (const float*)d_in[13];
  const float* o1_w   = (const float*)d_in[14];
  const float* o1_b   = (const float*)d_in[15];
  const float* o2_w   = (const float*)d_in[16];
  const float* o2_b   = (const float*)d_in[17];
  float* out = (float*)d_out;               // fp32 output

  float* w = (float*)d_ws;
  float* Wh    = w + O_WH;
  float* f1    = w + O_F1;
  float* f2    = w + O_F2;
  float* f2s   = w + O_F2S;
  float* elo   = w + O_ELO;
  float* ehi   = w + O_EHI;
  float* ef1hi = w + O_EF1H;
  float* ef1lo = w + O_EF1L;
  float* w2    = w + O_W2;
  float* SnapLo  = w + O_SLO;
  float* SnapHi  = w + O_SHI;
  float* SnapLoS = w + O_SLOS;
  float* SnapHiS = w + O_SHIS;
  float* wrow  = w + O_WR;
  float* Upart = w + O_UP;
  int* jsort   = (int*)(w + O_JS);
  int* pstar   = (int*)(w + O_PS);
  __hip_bfloat16* enc4 = (__hip_bfloat16*)(w + O_E4);

  VGNN_27049704030896_kernel<<<dim3(NN, HH), 128, 0, stream>>>(
      embed, W_enc, a_esrc, a_edst, Wh, f1, f2, ef1hi, ef1lo);
  k_sortp<<<HH, 512, 0, stream>>>(f2, f1, f2s, jsort, elo, ehi, pstar);
  k_scanA<<<dim3(CC, HH, BB), 128, 0, stream>>>(data, jsort, elo, ehi, Wh,
                                                SnapLo, SnapHi, SnapLoS, SnapHiS);
  k_scanB<<<BB * HH, 128, 0, stream>>>(SnapLo, SnapHi, SnapLoS, SnapHiS);
  k_w2  <<<dim3(HE / 128, HH), 128, 0, stream>>>(W_dec, a_ddst, w2);
  k_row <<<dim3(LL, BB), 64, 0, stream>>>(data, Wh, pstar, jsort, elo, ehi,
                                          ef1hi, ef1lo, SnapLo, SnapHi,
                                          SnapLoS, SnapHiS, g_enc, b_enc, w2,
                                          enc4, wrow);
  k_acc <<<dim3(32, BB), 128, 0, stream>>>(data, enc4, wrow, Upart);
  k_final<<<BB, 128, 0, stream>>>(Upart, wrow, W_dec, g_dec, b_dec,
                                  V_w, V_b, o1_w, o1_b, o2_w, o2_b, out);
}

// Round 21
// 246.095 us; speedup vs baseline: 42.5243x; 1.2132x over previous
//
#include <hip/hip_runtime.h>
#include <hip/hip_bf16.h>

#define BB 16
#define LL 1024
#define EE 128
#define HH 4
#define DD 128
#define NN 1025
#define HE 512
#define AL 0.2f
#define EPSV 1e-6f
#define SS 8
#define CC 128
#define C1 129

// workspace float offsets (total ~8.1M floats = 32.3 MB; ws >= 36.3 MB verified R9)
#define O_WH   0
#define O_F1   524800
#define O_F2   528900
#define O_F2S  533000
#define O_ELO  537096
#define O_EHI  541192
#define O_EF1H 545288
#define O_EF1L 549384
#define O_W2   553480
#define O_SLO  555528
#define O_SHI  1612296
#define O_SLOS 2669064
#define O_SHIS 2677320
#define O_WR   2685576
#define O_UP   2751112
#define O_JS   3799688
#define O_PS   3803784
#define O_E4   3807880
#define O_U    4856456
#define O_ZA   4889224
#define O_DP   4889352

// ---- K1: Wh + f1/f2 + exp tables (fused) -----------------------------------
__global__ void VGNN_27049704030896_kernel(const float* embed, const float* W_enc,
                                           const float* a_src, const float* a_dst,
                                           float* Wh, float* f1, float* f2,
                                           float* ef1hi, float* ef1lo) {
  __shared__ float r1[EE];
  __shared__ float r2[EE];
  int n = blockIdx.x;
  int h = blockIdx.y;
  int f = threadIdx.x;
  float acc = 0.0f;
  if (n > 0) {
    for (int e = 0; e < EE; e++) {
      acc += embed[n * EE + e] * W_enc[(h * EE + e) * EE + f];
    }
  }
  Wh[(h * NN + n) * EE + f] = acc;
  r1[f] = acc * a_src[h * EE + f];
  r2[f] = acc * a_dst[h * EE + f];
  __syncthreads();
  for (int s = 64; s > 0; s >>= 1) {
    if (f < s) { r1[f] += r1[f + s]; r2[f] += r2[f + s]; }
    __syncthreads();
  }
  if (f == 0) {
    f1[h * NN + n] = r1[0];
    f2[h * NN + n] = r2[0];
    if (n < LL) {
      ef1hi[h * LL + n] = expf(r1[0]);
      ef1lo[h * LL + n] = expf(AL * r1[0]);
    }
  }
}

// ---- K2: bitonic sort + exp tables + pstar binary search (fused) ----------
__global__ void k_sortp(const float* f2, const float* f1,
                        float* f2s, int* jsort, float* elo, float* ehi,
                        int* pstar) {
  __shared__ float key[LL];
  __shared__ int idx[LL];
  int h = blockIdx.x;
  int t = threadIdx.x;   // 512 threads
  key[t] = f2[h * NN + t];             idx[t] = t;
  key[t + 512] = f2[h * NN + t + 512]; idx[t + 512] = t + 512;
  for (int k = 2; k <= LL; k <<= 1) {
    for (int j = k >> 1; j > 0; j >>= 1) {
      __syncthreads();
      int i = ((t / j) * (j * 2)) + (t % j);
      int p = i + j;
      int up = ((i & k) == 0) ? 1 : 0;
      float a = key[i];
      float b2 = key[p];
      int sw = 0;
      if (up == 1) { if (a > b2) sw = 1; }
      else { if (a < b2) sw = 1; }
      if (sw == 1) {
        key[i] = b2; key[p] = a;
        int tm = idx[i]; idx[i] = idx[p]; idx[p] = tm;
      }
    }
  }
  __syncthreads();
  for (int q = t; q < LL; q += 512) {
    float kv = key[q];
    f2s[h * LL + q] = kv;
    jsort[h * LL + q] = idx[q];
    elo[h * LL + q] = expf(AL * kv);
    ehi[h * LL + q] = expf(kv);
  }
  for (int q = t; q < LL; q += 512) {
    float tg = -f1[h * NN + q];
    int lo = 0;
    int hi = LL;
    while (lo < hi) {
      int m = (lo + hi) >> 1;
      if (key[m] < tg) lo = m + 1; else hi = m;
    }
    pstar[h * LL + q] = lo;
  }
}

// ---- K3: per-chunk masked weighted totals into snapshot slots -------------
__global__ void k_scanA(const int* data, const int* jsort, const float* elo,
                        const float* ehi, const float* Wh,
                        float* SnapLo, float* SnapHi,
                        float* SnapLoS, float* SnapHiS) {
  int c = blockIdx.x;
  int h = blockIdx.y;
  int b = blockIdx.z;
  int f = threadIdx.x;
  int bh = b * HH + h;
  float alo = 0.0f; float ahi = 0.0f; float slo = 0.0f; float shi = 0.0f;
  for (int r = 0; r < SS; r++) {
    int p = c * SS + r;
    int j = jsort[h * LL + p];
    if (data[b * LL + j] != 0) {
      float wl = elo[h * LL + p];
      float wh2 = ehi[h * LL + p];
      float v = Wh[(h * NN + j) * EE + f];
      alo += wl * v; ahi += wh2 * v; slo += wl; shi += wh2;
    }
  }
  int o = bh * C1 + c;
  SnapLo[(long)o * EE + f] = alo;
  SnapHi[(long)o * EE + f] = ahi;
  if (f == 0) { SnapLoS[o] = slo; SnapHiS[o] = shi; }
}

// ---- K4: in-place exclusive scan of snapshots; total at slot CC -----------
__global__ void k_scanB(float* SnapLo, float* SnapHi,
                        float* SnapLoS, float* SnapHiS) {
  int bh = blockIdx.x;
  int f = threadIdx.x;
  float rl = 0.0f; float rh = 0.0f; float rls = 0.0f; float rhs = 0.0f;
  for (int c = 0; c < CC; c++) {
    int o = bh * C1 + c;
    float tl = SnapLo[(long)o * EE + f];
    float th = SnapHi[(long)o * EE + f];
    SnapLo[(long)o * EE + f] = rl;
    SnapHi[(long)o * EE + f] = rh;
    rl += tl; rh += th;
    if (f == 0) {
      float sl = SnapLoS[o]; float sh = SnapHiS[o];
      SnapLoS[o] = rls; SnapHiS[o] = rhs;
      rls += sl; rhs += sh;
    }
  }
  int o = bh * C1 + CC;
  SnapLo[(long)o * EE + f] = rl;
  SnapHi[(long)o * EE + f] = rh;
  if (f == 0) { SnapLoS[o] = rls; SnapHiS[o] = rhs; }
}

// ---- K5: w2[h,k] = sum_d W_dec[h,k,d] * a_dec_dst[h,d] --------------------
__global__ void k_w2(const float* W_dec, const float* a_vec, float* w2) {
  int k = blockIdx.x * 128 + threadIdx.x;
  int h = blockIdx.y;
  float s = 0.0f;
  for (int d = 0; d < DD; d++) {
    s += W_dec[(h * HE + k) * DD + d] * a_vec[h * DD + d];
  }
  w2[h * HE + k] = s;
}

// ---- K6: wave-per-row: prefix-attn -> LN -> elu -> e4(bf16), g2 -> wrow ---
__global__ void k_row(const int* data, const float* Wh, const int* pstar,
                      const int* jsort, const float* elo, const float* ehi,
                      const float* ef1hi, const float* ef1lo,
                      const float* SnapLo, const float* SnapHi,
                      const float* SnapLoS, const float* SnapHiS,
                      const float* g_enc, const float* b_enc, const float* w2,
                      __hip_bfloat16* enc4, float* wrow) {
  int i = blockIdx.x;
  int b = blockIdx.y;
  int t = threadIdx.x;   // 64 threads = 1 wave; features t and t+64
  if (data[b * LL + i] == 0) {
    if (t < HH) wrow[(b * HH + t) * LL + i] = 0.0f;
    return;
  }
  __shared__ float red[64];
  __shared__ float red4[HH][64];
  float x0[HH];
  float x1[HH];
  for (int h = 0; h < HH; h++) {
    int p = pstar[h * LL + i];
    int c = p / SS;
    int bh = b * HH + h;
    int o = bh * C1 + c;
    float rl0 = SnapLo[(long)o * EE + t];
    float rl1 = SnapLo[(long)o * EE + t + 64];
    float rh0 = SnapHi[(long)o * EE + t];
    float rh1 = SnapHi[(long)o * EE + t + 64];
    float rls = SnapLoS[o];
    float rhs = SnapHiS[o];
    int q0 = c * SS;
    int np = p - q0;
#pragma unroll
    for (int r = 0; r < 7; r++) {
      if (r < np) {
        int j = jsort[h * LL + q0 + r];
        if (data[b * LL + j] != 0) {
          float wl = elo[h * LL + q0 + r];
          float wh2 = ehi[h * LL + q0 + r];
          float v0 = Wh[(h * NN + j) * EE + t];
          float v1 = Wh[(h * NN + j) * EE + t + 64];
          rl0 += wl * v0; rl1 += wl * v1;
          rh0 += wh2 * v0; rh1 += wh2 * v1;
          rls += wl; rhs += wh2;
        }
      }
    }
    int ot = bh * C1 + CC;
    float Th0 = SnapHi[(long)ot * EE + t];
    float Th1 = SnapHi[(long)ot * EE + t + 64];
    float Ths = SnapHiS[ot];
    float eh = ef1hi[h * LL + i];
    float el = ef1lo[h * LL + i];
    float den = eh * (Ths - rhs) + el * rls;
    float v0 = (eh * (Th0 - rh0) + el * rl0) / den;
    float v1 = (eh * (Th1 - rh1) + el * rl1) / den;
    x0[h] = (v0 > 0.0f) ? v0 : (expf(v0) - 1.0f);
    x1[h] = (v1 > 0.0f) ? v1 : (expf(v1) - 1.0f);
  }
  float loc = 0.0f;
  for (int h = 0; h < HH; h++) loc += x0[h] + x1[h];
  red[t] = loc;
  __syncthreads();
  for (int s = 32; s > 0; s >>= 1) {
    if (t < s) red[t] += red[t + s];
    __syncthreads();
  }
  float mu = red[0] / 512.0f;
  __syncthreads();
  float q2 = 0.0f;
  for (int h = 0; h < HH; h++) {
    float d0 = x0[h] - mu; float d1 = x1[h] - mu;
    q2 += d0 * d0 + d1 * d1;
  }
  red[t] = q2;
  __syncthreads();
  for (int s = 32; s > 0; s >>= 1) {
    if (t < s) red[t] += red[t + s];
    __syncthreads();
  }
  float sd = sqrtf(red[0] / 511.0f);
  float inv = 1.0f / (sd + EPSV);
  float e40[HH];
  float e41[HH];
  long rowo = ((long)(b * LL + i)) * HE;
  for (int h = 0; h < HH; h++) {
    float v0 = g_enc[h * EE + t] * (x0[h] - mu) * inv + b_enc[h * EE + t];
    float v1 = g_enc[h * EE + t + 64] * (x1[h] - mu) * inv + b_enc[h * EE + t + 64];
    e40[h] = (v0 > 0.0f) ? v0 : (expf(v0) - 1.0f);
    e41[h] = (v1 > 0.0f) ? v1 : (expf(v1) - 1.0f);
    enc4[rowo + h * EE + t] = __float2bfloat16(e40[h]);
    enc4[rowo + h * EE + t + 64] = __float2bfloat16(e41[h]);
  }
  for (int hp = 0; hp < HH; hp++) {
    float p = 0.0f;
    for (int h = 0; h < HH; h++) {
      p += e40[h] * w2[hp * HE + h * EE + t];
      p += e41[h] * w2[hp * HE + h * EE + t + 64];
    }
    red4[hp][t] = p;
  }
  __syncthreads();
  for (int s = 32; s > 0; s >>= 1) {
    if (t < s) {
      red4[0][t] += red4[0][t + s];
      red4[1][t] += red4[1][t + s];
      red4[2][t] += red4[2][t + s];
      red4[3][t] += red4[3][t + s];
    }
    __syncthreads();
  }
  if (t < HH) {
    float g = red4[t][0];
    if (g < 0.0f) g = AL * g;
    wrow[(b * HH + t) * LL + i] = expf(g);
  }
}

// ---- K7: stream e4 rows, write per-chunk U partials (no atomics) ----------
__global__ void k_acc(const int* data, const __hip_bfloat16* enc4,
                      const float* wrow, float* Upart) {
  __shared__ float Us[HH * HE];
  int c = blockIdx.x;
  int b = blockIdx.y;
  int f = threadIdx.x;
  for (int k = f; k < HH * HE; k += EE) Us[k] = 0.0f;
  __syncthreads();
  for (int r = 0; r < 32; r++) {
    int i = c * 32 + r;
    if (data[b * LL + i] == 0) continue;
    float w0 = wrow[(b * HH + 0) * LL + i];
    float w1 = wrow[(b * HH + 1) * LL + i];
    float w2v = wrow[(b * HH + 2) * LL + i];
    float w3 = wrow[(b * HH + 3) * LL + i];
    for (int m = 0; m < 4; m++) {
      float e = __bfloat162float(enc4[((long)(b * LL + i)) * HE + m * EE + f]);
      Us[0 * HE + m * EE + f] += w0 * e;
      Us[1 * HE + m * EE + f] += w1 * e;
      Us[2 * HE + m * EE + f] += w2v * e;
      Us[3 * HE + m * EE + f] += w3 * e;
    }
  }
  __syncthreads();
  long base = (long)(b * 32 + c) * (HH * HE);
  for (int k = f; k < HH * HE; k += EE) Upart[base + k] = Us[k];
}

// ---- K8a: sum 32 U partials -> U[b,2048]; z from wrow ---------------------
__global__ void k_usum(const float* Upart, const float* wrow,
                       float* U, float* zacc) {
  __shared__ float red[256];
  int b = blockIdx.x;
  int t = threadIdx.x;   // 256
  for (int k = t; k < HH * HE; k += 256) {
    float s = 0.0f;
    for (int c = 0; c < 32; c++) {
      s += Upart[(long)(b * 32 + c) * (HH * HE) + k];
    }
    U[b * (HH * HE) + k] = s;
  }
  for (int hp = 0; hp < HH; hp++) {
    float p = 0.0f;
    for (int q = t; q < LL; q += 256) p += wrow[(b * HH + hp) * LL + q];
    red[t] = p;
    __syncthreads();
    for (int s = 128; s > 0; s >>= 1) {
      if (t < s) red[t] += red[t + s];
      __syncthreads();
    }
    if (t == 0) zacc[b * HH + hp] = red[0];
    __syncthreads();
  }
}

// ---- K8b: decPart[b,cK,f] = 0.25 * sum_{k in chunk} U[k] W_dec[k,f]/(1+z) -
__global__ void k_dmv(const float* U, const float* zacc, const float* W_dec,
                      float* decPart) {
  __shared__ float Uc[128];
  int cK = blockIdx.x;   // 16 chunks of 128 k (chunk stays within one head)
  int b = blockIdx.y;
  int f = threadIdx.x;   // 128
  int k0 = cK * 128;
  int h = cK / 4;
  Uc[f] = U[b * (HH * HE) + k0 + f];
  __syncthreads();
  float zinv = 1.0f / (1.0f + zacc[b * HH + h]);
  float s = 0.0f;
  for (int kk = 0; kk < 128; kk++) {
    s += Uc[kk] * W_dec[(long)(k0 + kk) * DD + f];
  }
  decPart[(long)(b * 16 + cK) * DD + f] = 0.25f * s * zinv;
}

// ---- K8c: finalize: sum decParts, LN, relu, V, o1, o2 (fp32 out) ----------
__global__ void k_finB(const float* decPart,
                       const float* g_dec, const float* b_dec,
                       const float* V_w, const float* V_b,
                       const float* o1_w, const float* o1_b,
                       const float* o2_w, const float* o2_b,
                       float* out) {
  __shared__ float red[DD];
  __shared__ float xs[DD];
  int b = blockIdx.x;
  int f = threadIdx.x;   // 128
  float dec = 0.0f;
  for (int cK = 0; cK < 16; cK++) {
    dec += decPart[(long)(b * 16 + cK) * DD + f];
  }
  red[f] = dec;
  __syncthreads();
  for (int s = 64; s > 0; s >>= 1) {
    if (f < s) red[f] += red[f + s];
    __syncthreads();
  }
  float mu = red[0] / 128.0f;
  __syncthreads();
  float dd = dec - mu;
  red[f] = dd * dd;
  __syncthreads();
  for (int s = 64; s > 0; s >>= 1) {
    if (f < s) red[f] += red[f + s];
    __syncthreads();
  }
  float sd = sqrtf(red[0] / 127.0f);
  float t = g_dec[f] * dd / (sd + EPSV) + b_dec[f];
  if (t < 0.0f) t = 0.0f;
  __syncthreads();
  xs[f] = t;
  __syncthreads();
  float xv = 0.0f;
  for (int k = 0; k < DD; k++) xv += xs[k] * V_w[k * DD + f];
  xv += V_b[f];
  __syncthreads();
  xs[f] = xv;
  __syncthreads();
  float hv = 0.0f;
  for (int k = 0; k < DD; k++) hv += xs[k] * o1_w[k * DD + f];
  hv += o1_b[f];
  if (hv < 0.0f) hv = 0.0f;
  red[f] = hv * o2_w[f];
  __syncthreads();
  for (int s = 64; s > 0; s >>= 1) {
    if (f < s) red[f] += red[f + s];
    __syncthreads();
  }
  if (f == 0) out[b] = red[0] + o2_b[0];
}

extern "C" void kernel_launch(void* const* d_in, const int* in_sizes, int n_in,
                              void* d_out, int out_size, void* d_ws, size_t ws_size,
                              hipStream_t stream) {
  const int* data    = (const int*)d_in[0];
  const float* embed  = (const float*)d_in[1];
  const float* W_enc  = (const float*)d_in[2];
  const float* a_esrc = (const float*)d_in[3];
  const float* a_edst = (const float*)d_in[4];
  const float* g_enc  = (const float*)d_in[5];
  const float* b_enc  = (const float*)d_in[6];
  const float* W_dec  = (const float*)d_in[7];
  const float* a_ddst = (const float*)d_in[9];
  const float* g_dec  = (const float*)d_in[10];
  const float* b_dec  = (const float*)d_in[11];
  const float* V_w    = (const float*)d_in[12];
  const float* V_b    = (const float*)d_in[13];
  const float* o1_w   = (const float*)d_in[14];
  const float* o1_b   = (const float*)d_in[15];
  const float* o2_w   = (const float*)d_in[16];
  const float* o2_b   = (const float*)d_in[17];
  float* out = (float*)d_out;               // fp32 output

  float* w = (float*)d_ws;
  float* Wh    = w + O_WH;
  float* f1    = w + O_F1;
  float* f2    = w + O_F2;
  float* f2s   = w + O_F2S;
  float* elo   = w + O_ELO;
  float* ehi   = w + O_EHI;
  float* ef1hi = w + O_EF1H;
  float* ef1lo = w + O_EF1L;
  float* w2    = w + O_W2;
  float* SnapLo  = w + O_SLO;
  float* SnapHi  = w + O_SHI;
  float* SnapLoS = w + O_SLOS;
  float* SnapHiS = w + O_SHIS;
  float* wrow  = w + O_WR;
  float* Upart = w + O_UP;
  int* jsort   = (int*)(w + O_JS);
  int* pstar   = (int*)(w + O_PS);
  __hip_bfloat16* enc4 = (__hip_bfloat16*)(w + O_E4);
  float* U     = w + O_U;
  float* zacc  = w + O_ZA;
  float* decPart = w + O_DP;

  VGNN_27049704030896_kernel<<<dim3(NN, HH), 128, 0, stream>>>(
      embed, W_enc, a_esrc, a_edst, Wh, f1, f2, ef1hi, ef1lo);
  k_sortp<<<HH, 512, 0, stream>>>(f2, f1, f2s, jsort, elo, ehi, pstar);
  k_scanA<<<dim3(CC, HH, BB), 128, 0, stream>>>(data, jsort, elo, ehi, Wh,
                                                SnapLo, SnapHi, SnapLoS, SnapHiS);
  k_scanB<<<BB * HH, 128, 0, stream>>>(SnapLo, SnapHi, SnapLoS, SnapHiS);
  k_w2  <<<dim3(HE / 128, HH), 128, 0, stream>>>(W_dec, a_ddst, w2);
  k_row <<<dim3(LL, BB), 64, 0, stream>>>(data, Wh, pstar, jsort, elo, ehi,
                                          ef1hi, ef1lo, SnapLo, SnapHi,
                                          SnapLoS, SnapHiS, g_enc, b_enc, w2,
                                          enc4, wrow);
  k_acc <<<dim3(32, BB), 128, 0, stream>>>(data, enc4, wrow, Upart);
  k_usum<<<BB, 256, 0, stream>>>(Upart, wrow, U, zacc);
  k_dmv <<<dim3(16, BB), 128, 0, stream>>>(U, zacc, W_dec, decPart);
  k_finB<<<BB, 128, 0, stream>>>(decPart, g_dec, b_dec, V_w, V_b,
                                 o1_w, o1_b, o2_w, o2_b, out);
}